// Round 6
// baseline (4316.757 us; speedup 1.0000x reference)
//
#include <hip/hip_runtime.h>

#define BB 4096
#define TD 5000
#define NN 200000
#define EE 6400000

__device__ __forceinline__ void atomAddF(float* p, float v) {
    unsafeAtomicAdd(p, v);
}

// ---------------- utility ----------------
__global__ void k_zero(float* p, int n) {
    int i = blockIdx.x * 256 + threadIdx.x;
    if (i < n) p[i] = 0.f;
}

// Detect edge dtype: if int64, every odd int32 word (high word of a non-negative
// int64 < 2^31) is 0. For int32 edges those words are edge values — 4096 of them
// all being zero is impossible. flag=1 -> int64, flag=0 -> int32.
__global__ void k_detect(const int* __restrict__ e, int* __restrict__ flag) {
    __shared__ int r[256];
    int tid = threadIdx.x;
    int acc = 0;
    for (int i = tid; i < 4096; i += 256) acc |= e[2 * i + 1];
    r[tid] = acc;
    __syncthreads();
    for (int s = 128; s > 0; s >>= 1) {
        if (tid < s) r[tid] |= r[tid + s];
        __syncthreads();
    }
    if (tid == 0) *flag = (r[0] == 0) ? 1 : 0;
}

__global__ void k_deg_init(unsigned int* deg) {
    int i = blockIdx.x * 256 + threadIdx.x;
    if (i < NN) deg[i] = 1u;  // self loop
}
__global__ void k_deg_count(const int* __restrict__ edge, const int* __restrict__ flag,
                            unsigned int* __restrict__ deg) {
    int e = blockIdx.x * 256 + threadIdx.x;
    if (e >= EE) return;
    int f = *flag;
    int d = f ? edge[2 * (EE + e)] : edge[EE + e];
    atomicAdd(&deg[d], 1u);
}
// in-place: deg (u32) -> dinv (f32), same buffer
__global__ void k_dinv(unsigned int* __restrict__ degdinv) {
    int i = blockIdx.x * 256 + threadIdx.x;
    if (i < NN) {
        float d = (float)degdinv[i];
        ((float*)degdinv)[i] = rsqrtf(d);
    }
}

// ---------------- GCN ----------------
// h0 = node_x @ Wg1  (128 -> 8, no bias yet)
__global__ __launch_bounds__(256) void k_gcn1_mm(
    const float* __restrict__ nodex, const float* __restrict__ Wg1,
    float* __restrict__ h0)
{
    __shared__ float W[128 * 8];
    int tid = threadIdx.x;
    for (int i = tid; i < 1024; i += 256) W[i] = Wg1[i];
    __syncthreads();
    int row = blockIdx.x * 256 + tid;
    if (row >= NN) return;
    const float4* xr = (const float4*)(nodex + (size_t)row * 128);
    float acc[8];
#pragma unroll
    for (int j = 0; j < 8; j++) acc[j] = 0.f;
#pragma unroll 8
    for (int c = 0; c < 32; c++) {
        float4 v = xr[c];
        const float* wr = &W[c * 32];
#pragma unroll
        for (int j = 0; j < 8; j++)
            acc[j] += v.x * wr[j] + v.y * wr[8 + j] + v.z * wr[16 + j] + v.w * wr[24 + j];
    }
    float* o = h0 + (size_t)row * 8;
#pragma unroll
    for (int j = 0; j < 8; j++) o[j] = acc[j];
}

__global__ __launch_bounds__(256) void k_gcn1_agg(
    const int* __restrict__ edge, const int* __restrict__ flag,
    const float* __restrict__ dinv, const float* __restrict__ h0,
    float* __restrict__ acc1)
{
    int e = blockIdx.x * 256 + threadIdx.x;
    if (e >= EE) return;
    int f = *flag;
    int s = f ? edge[2 * e] : edge[e];
    int d = f ? edge[2 * (EE + e)] : edge[EE + e];
    float w = dinv[s] * dinv[d];
    const float* hs = h0 + (size_t)s * 8;
    float* ad = acc1 + (size_t)d * 8;
#pragma unroll
    for (int j = 0; j < 8; j++) atomAddF(&ad[j], hs[j] * w);
}

// h1 = relu(acc1 + self*d2 + bg1); h2lin = h1 @ Wg2  (8 -> 4)
__global__ __launch_bounds__(256) void k_gcn1_post(
    const float* __restrict__ acc1, const float* __restrict__ h0,
    const float* __restrict__ dinv, const float* __restrict__ bg1,
    const float* __restrict__ Wg2, float* __restrict__ h2lin)
{
    __shared__ float W[32];
    __shared__ float bb[8];
    int tid = threadIdx.x;
    if (tid < 32) W[tid] = Wg2[tid];
    if (tid < 8) bb[tid] = bg1[tid];
    __syncthreads();
    int i = blockIdx.x * 256 + tid;
    if (i >= NN) return;
    float di = dinv[i];
    float d2 = di * di;
    float v[8];
#pragma unroll
    for (int j = 0; j < 8; j++)
        v[j] = fmaxf(acc1[(size_t)i * 8 + j] + h0[(size_t)i * 8 + j] * d2 + bb[j], 0.f);
#pragma unroll
    for (int j2 = 0; j2 < 4; j2++) {
        float s = 0.f;
#pragma unroll
        for (int k = 0; k < 8; k++) s += v[k] * W[k * 4 + j2];
        h2lin[(size_t)i * 4 + j2] = s;
    }
}

__global__ __launch_bounds__(256) void k_gcn2_agg(
    const int* __restrict__ edge, const int* __restrict__ flag,
    const float* __restrict__ dinv, const float* __restrict__ h2lin,
    float* __restrict__ acc2)
{
    int e = blockIdx.x * 256 + threadIdx.x;
    if (e >= EE) return;
    int f = *flag;
    int s = f ? edge[2 * e] : edge[e];
    int d = f ? edge[2 * (EE + e)] : edge[EE + e];
    float w = dinv[s] * dinv[d];
    const float* hs = h2lin + (size_t)s * 4;
    float* ad = acc2 + (size_t)d * 4;
#pragma unroll
    for (int j = 0; j < 4; j++) atomAddF(&ad[j], hs[j] * w);
}

__global__ __launch_bounds__(256) void k_gcn2_post_pool(
    const float* __restrict__ acc2, const float* __restrict__ h2lin,
    const float* __restrict__ dinv, const float* __restrict__ bg2,
    const int* __restrict__ batch, const int* __restrict__ flag,
    float* __restrict__ pool, float* __restrict__ cnt)
{
    __shared__ float bb[4];
    if (threadIdx.x < 4) bb[threadIdx.x] = bg2[threadIdx.x];
    __syncthreads();
    int i = blockIdx.x * 256 + threadIdx.x;
    if (i >= NN) return;
    int f = *flag;
    float di = dinv[i];
    float d2 = di * di;
    int b = f ? batch[2 * i] : batch[i];
    float* pb = pool + (size_t)b * 4;
#pragma unroll
    for (int j = 0; j < 4; j++) {
        float h = acc2[(size_t)i * 4 + j] + h2lin[(size_t)i * 4 + j] * d2 + bb[j];
        atomAddF(&pb[j], h);
    }
    atomAddF(&cnt[b], 1.f);
}

// ---------------- AE encode: z_text (f32, into scratch) ----------------
__global__ __launch_bounds__(256) void k_ae_encode(
    const float* __restrict__ text,
    const float* __restrict__ We1, const float* __restrict__ be1,
    const float* __restrict__ We2, const float* __restrict__ be2,
    float* __restrict__ z_text)
{
    __shared__ float red[8][256];
    __shared__ float t1[8];
    int row = blockIdx.x, tid = threadIdx.x;
    const float* xrow = text + (size_t)row * TD;
    float acc[8];
#pragma unroll
    for (int j = 0; j < 8; j++) acc[j] = 0.f;
    for (int i = tid; i < TD; i += 256) {
        float x = xrow[i];
        const float* wr = We1 + (size_t)i * 8;
#pragma unroll
        for (int j = 0; j < 8; j++) acc[j] += x * wr[j];
    }
#pragma unroll
    for (int j = 0; j < 8; j++) red[j][tid] = acc[j];
    __syncthreads();
    for (int s = 128; s > 0; s >>= 1) {
        if (tid < s) {
#pragma unroll
            for (int j = 0; j < 8; j++) red[j][tid] += red[j][tid + s];
        }
        __syncthreads();
    }
    if (tid < 8) t1[tid] = fmaxf(red[tid][0] + be1[tid], 0.f);
    __syncthreads();
    if (tid < 4) {
        float z = be2[tid];
#pragma unroll
        for (int k = 0; k < 8; k++) z += t1[k] * We2[k * 4 + tid];
        z_text[row * 4 + tid] = fmaxf(z, 0.f);
    }
}

// ---------------- final head: logits + z (f32, into real output area) ----------------
__global__ __launch_bounds__(256) void k_final(
    const float* __restrict__ z_text, const float* __restrict__ pool,
    const float* __restrict__ cnt, const float* __restrict__ Wc,
    const float* __restrict__ bc, float* __restrict__ out_logits,
    float* __restrict__ out_z)
{
    int g = blockIdx.x * 256 + threadIdx.x;
    if (g >= BB) return;
    float c = fmaxf(cnt[g], 1.f);
    float z8[8];
#pragma unroll
    for (int j = 0; j < 4; j++) z8[j] = z_text[g * 4 + j];
#pragma unroll
    for (int j = 0; j < 4; j++) z8[4 + j] = pool[g * 4 + j] / c;
    float l = bc[0];
#pragma unroll
    for (int k = 0; k < 8; k++) l += z8[k] * Wc[k];
    out_logits[g] = l;
#pragma unroll
    for (int k = 0; k < 8; k++) out_z[g * 8 + k] = z8[k];
}

// ---------------- AE decode: x_hat (f32) overwrites the whole scratch region ----------------
__global__ __launch_bounds__(256) void k_ae_decode(
    const float* __restrict__ out_z,
    const float* __restrict__ Wd1, const float* __restrict__ bd1,
    const float* __restrict__ Wd2, const float* __restrict__ bd2,
    float* __restrict__ xhat)
{
    int row = blockIdx.x, tid = threadIdx.x;
    float zz[4];
#pragma unroll
    for (int j = 0; j < 4; j++) zz[j] = out_z[row * 8 + j];
    float t[8];
#pragma unroll
    for (int k = 0; k < 8; k++) {
        float s = bd1[k];
#pragma unroll
        for (int j = 0; j < 4; j++) s += zz[j] * Wd1[j * 8 + k];
        t[k] = fmaxf(s, 0.f);
    }
    float* orow = xhat + (size_t)row * TD;
    for (int c = tid; c < TD; c += 256) {
        float s = bd2[c];
#pragma unroll
        for (int k = 0; k < 8; k++) s += t[k] * Wd2[(size_t)k * TD + c];
        orow[c] = 1.f / (1.f + expf(-s));
    }
}

extern "C" void kernel_launch(void* const* d_in, const int* in_sizes, int n_in,
                              void* d_out, int out_size, void* d_ws, size_t ws_size,
                              hipStream_t stream) {
    const float* text  = (const float*)d_in[0];
    const float* nodex = (const float*)d_in[1];
    const int* edge    = (const int*)d_in[2];
    const int* batch   = (const int*)d_in[3];
    const float* We1 = (const float*)d_in[4];
    const float* be1 = (const float*)d_in[5];
    const float* We2 = (const float*)d_in[6];
    const float* be2 = (const float*)d_in[7];
    const float* Wd1 = (const float*)d_in[8];
    const float* bd1 = (const float*)d_in[9];
    const float* Wd2 = (const float*)d_in[10];
    const float* bd2 = (const float*)d_in[11];
    const float* Wg1 = (const float*)d_in[12];
    const float* bg1 = (const float*)d_in[13];
    const float* Wg2 = (const float*)d_in[14];
    const float* bg2 = (const float*)d_in[15];
    const float* Wc  = (const float*)d_in[16];
    const float* bc  = (const float*)d_in[17];

    // ---- d_out is 20,516,864 FLOAT32 elements (82,067,456 bytes).
    // ---- All scratch lives in the f32 x_hat region (first 81,920,000 bytes);
    // ---- k_ae_decode overwrites it with f32 x_hat at the very end. d_ws unused.
    char* sc = (char*)d_out;
    float* acc1 = (float*)(sc + 0);            // N*8 f32 = 6,400,000 B
    float* h0   = (float*)(sc + 6400000);      // N*8 f32
    float* h2   = (float*)(sc + 12800000);     // N*4 f32
    float* acc2 = (float*)(sc + 16000000);     // N*4 f32
    float* dinv = (float*)(sc + 19200000);     // N f32 (aliased deg u32 -> dinv f32)
    unsigned int* deg = (unsigned int*)dinv;
    float* pool   = (float*)(sc + 20000000);   // B*4 f32 = 65,536 B
    float* cnt    = (float*)(sc + 20065536);   // B f32   = 16,384 B
    float* z_text = (float*)(sc + 20081920);   // B*4 f32 = 65,536 B
    int*   flag   = (int*)  (sc + 20147456);   // 4 B
    // scratch ends ~20.15 MB < 81.92 MB (start of out_logits)

    float* out_xhat   = (float*)d_out;                 // B*TD f32
    float* out_logits = out_xhat + (size_t)BB * TD;    // B
    float* out_z      = out_logits + BB;               // B*8

    const int NB_N = (NN + 255) / 256;   // 782
    const int NB_E = EE / 256;           // 25000

    k_zero<<<(NN * 8 + 255) / 256, 256, 0, stream>>>(acc1, NN * 8);
    k_zero<<<(NN * 4 + 255) / 256, 256, 0, stream>>>(acc2, NN * 4);
    k_zero<<<(BB * 5 + 255) / 256, 256, 0, stream>>>(pool, BB * 5);  // pool+cnt contiguous

    k_detect<<<1, 256, 0, stream>>>(edge, flag);
    k_deg_init<<<NB_N, 256, 0, stream>>>(deg);
    k_deg_count<<<NB_E, 256, 0, stream>>>(edge, flag, deg);
    k_dinv<<<NB_N, 256, 0, stream>>>(deg);

    k_gcn1_mm<<<NB_N, 256, 0, stream>>>(nodex, Wg1, h0);
    k_gcn1_agg<<<NB_E, 256, 0, stream>>>(edge, flag, dinv, h0, acc1);
    k_gcn1_post<<<NB_N, 256, 0, stream>>>(acc1, h0, dinv, bg1, Wg2, h2);
    k_gcn2_agg<<<NB_E, 256, 0, stream>>>(edge, flag, dinv, h2, acc2);
    k_gcn2_post_pool<<<NB_N, 256, 0, stream>>>(acc2, h2, dinv, bg2, batch, flag, pool, cnt);

    k_ae_encode<<<BB, 256, 0, stream>>>(text, We1, be1, We2, be2, z_text);
    k_final<<<(BB + 255) / 256, 256, 0, stream>>>(z_text, pool, cnt, Wc, bc,
                                                  out_logits, out_z);
    // decode LAST: reads z from out_z (f32), overwrites all scratch with f32 x_hat
    k_ae_decode<<<BB, 256, 0, stream>>>(out_z, Wd1, bd1, Wd2, bd2, out_xhat);
}

// Round 7
// 832.556 us; speedup vs baseline: 5.1849x; 5.1849x over previous
//
#include <hip/hip_runtime.h>

#define BB 4096
#define TD 5000
#define NN 200000
#define EE 6400000
#define NBK 782  // ceil(NN/256)

__device__ __forceinline__ void atomAddF(float* p, float v) {
    unsafeAtomicAdd(p, v);
}

// ---------------- utility ----------------
__global__ void k_zero(float* p, int n) {
    int i = blockIdx.x * 256 + threadIdx.x;
    if (i < n) p[i] = 0.f;
}

// Detect edge dtype: int64 -> every odd int32 word is 0 (values < 2^31).
__global__ void k_detect(const int* __restrict__ e, int* __restrict__ flag) {
    __shared__ int r[256];
    int tid = threadIdx.x;
    int acc = 0;
    for (int i = tid; i < 4096; i += 256) acc |= e[2 * i + 1];
    r[tid] = acc;
    __syncthreads();
    for (int s = 128; s > 0; s >>= 1) {
        if (tid < s) r[tid] |= r[tid + s];
        __syncthreads();
    }
    if (tid == 0) *flag = (r[0] == 0) ? 1 : 0;
}

__global__ void k_deg_init(unsigned int* deg) {
    int i = blockIdx.x * 256 + threadIdx.x;
    if (i < NN) deg[i] = 1u;  // self loop
}

// ONE atomic pass: rank of edge within its dst + final degree count.
// deg init = 1 (self loop), so returned old value r >= 1; local rank = r-1.
__global__ void k_rank(const int* __restrict__ edge, const int* __restrict__ flag,
                       unsigned int* __restrict__ deg, unsigned int* __restrict__ r) {
    int e = blockIdx.x * 256 + threadIdx.x;
    if (e >= EE) return;
    int f = *flag;
    int d = f ? edge[2 * (EE + e)] : edge[EE + e];
    r[e] = atomicAdd(&deg[d], 1u);
}

__global__ void k_dinv(const unsigned int* __restrict__ deg, float* __restrict__ dinv) {
    int i = blockIdx.x * 256 + threadIdx.x;
    if (i < NN) dinv[i] = rsqrtf((float)deg[i]);
}

// ---------------- indptr scan (3 kernels) ----------------
__global__ void kA_blocksum(const unsigned int* __restrict__ deg, unsigned int* __restrict__ bsum) {
    __shared__ unsigned int s[256];
    int tid = threadIdx.x;
    int i = blockIdx.x * 256 + tid;
    s[tid] = (i < NN) ? (deg[i] - 1u) : 0u;
    __syncthreads();
    for (int st = 128; st > 0; st >>= 1) {
        if (tid < st) s[tid] += s[tid + st];
        __syncthreads();
    }
    if (tid == 0) bsum[blockIdx.x] = s[0];
}
__global__ void kB_scanblocks(const unsigned int* __restrict__ bsum, unsigned int* __restrict__ bpre,
                              unsigned int* __restrict__ indptr) {
    __shared__ unsigned int s[1024];
    int t = threadIdx.x;
    s[t] = (t < NBK) ? bsum[t] : 0u;
    __syncthreads();
    for (int off = 1; off < 1024; off <<= 1) {
        unsigned int v = (t >= off) ? s[t - off] : 0u;
        __syncthreads();
        s[t] += v;
        __syncthreads();
    }
    if (t < NBK) bpre[t] = (t == 0) ? 0u : s[t - 1];
    if (t == 0) indptr[NN] = EE;
}
__global__ void kC_indptr(const unsigned int* __restrict__ deg, const unsigned int* __restrict__ bpre,
                          unsigned int* __restrict__ indptr) {
    __shared__ unsigned int s[256];
    int tid = threadIdx.x;
    int i = blockIdx.x * 256 + tid;
    unsigned int c = (i < NN) ? (deg[i] - 1u) : 0u;
    s[tid] = c;
    __syncthreads();
    for (int off = 1; off < 256; off <<= 1) {
        unsigned int v = (tid >= off) ? s[tid - off] : 0u;
        __syncthreads();
        s[tid] += v;
        __syncthreads();
    }
    if (i < NN) indptr[i] = bpre[blockIdx.x] + s[tid] - c;  // exclusive
}

// atomic-free placement
__global__ void k_place(const int* __restrict__ edge, const int* __restrict__ flag,
                        const unsigned int* __restrict__ indptr, const unsigned int* __restrict__ r,
                        int* __restrict__ csr_src) {
    int e = blockIdx.x * 256 + threadIdx.x;
    if (e >= EE) return;
    int f = *flag;
    int s = f ? edge[2 * e] : edge[e];
    int d = f ? edge[2 * (EE + e)] : edge[EE + e];
    csr_src[indptr[d] + r[e] - 1u] = s;
}

// ---------------- GCN ----------------
// h0g = dinv[i] * (node_x @ Wg1)   (128 -> 8)
__global__ __launch_bounds__(256) void k_gcn1_mm(
    const float* __restrict__ nodex, const float* __restrict__ Wg1,
    const float* __restrict__ dinv, float* __restrict__ h0g)
{
    __shared__ float W[128 * 8];
    int tid = threadIdx.x;
    for (int i = tid; i < 1024; i += 256) W[i] = Wg1[i];
    __syncthreads();
    int row = blockIdx.x * 256 + tid;
    if (row >= NN) return;
    const float4* xr = (const float4*)(nodex + (size_t)row * 128);
    float acc[8];
#pragma unroll
    for (int j = 0; j < 8; j++) acc[j] = 0.f;
#pragma unroll 8
    for (int c = 0; c < 32; c++) {
        float4 v = xr[c];
        const float* wr = &W[c * 32];
#pragma unroll
        for (int j = 0; j < 8; j++)
            acc[j] += v.x * wr[j] + v.y * wr[8 + j] + v.z * wr[16 + j] + v.w * wr[24 + j];
    }
    float di = dinv[row];
    float* o = h0g + (size_t)row * 8;
#pragma unroll
    for (int j = 0; j < 8; j++) o[j] = di * acc[j];
}

// wave per node: acc = h0g[i] + sum_{s in in(i)} h0g[s];
// h1 = relu(dinv*acc + b1); h2g = dinv * (h1 @ Wg2)
__global__ __launch_bounds__(256) void k_gather1(
    const unsigned int* __restrict__ indptr, const int* __restrict__ csr_src,
    const float* __restrict__ h0g, const float* __restrict__ dinv,
    const float* __restrict__ bg1, const float* __restrict__ Wg2,
    float* __restrict__ h2g)
{
    __shared__ float W[32];
    __shared__ float b1[8];
    __shared__ float h1s[4][8];
    int tid = threadIdx.x;
    if (tid < 32) W[tid] = Wg2[tid];
    if (tid < 8) b1[tid] = bg1[tid];
    __syncthreads();
    int wid = tid >> 6, lane = tid & 63;
    int i = blockIdx.x * 4 + wid;
    if (i < NN) {
        int beg = indptr[i], end = indptr[i + 1];
        int f = lane & 7;
        float a = 0.f;
        for (int k = beg + (lane >> 3); k < end; k += 8)
            a += h0g[(size_t)csr_src[k] * 8 + f];
        a += __shfl_xor(a, 8, 64);
        a += __shfl_xor(a, 16, 64);
        a += __shfl_xor(a, 32, 64);
        if (lane < 8) {
            float di = dinv[i];
            h1s[wid][f] = fmaxf(di * (a + h0g[(size_t)i * 8 + f]) + b1[f], 0.f);
        }
    }
    __syncthreads();
    if (i < NN && lane < 4) {
        float di = dinv[i];
        float s = 0.f;
#pragma unroll
        for (int k = 0; k < 8; k++) s += h1s[wid][k] * W[k * 4 + lane];
        h2g[(size_t)i * 4 + lane] = di * s;
    }
}

// wave per node: h2 = dinv*(h2g[i] + sum h2g[s]) + b2; pool by batch
__global__ __launch_bounds__(256) void k_gather2(
    const unsigned int* __restrict__ indptr, const int* __restrict__ csr_src,
    const float* __restrict__ h2g, const float* __restrict__ dinv,
    const float* __restrict__ bg2, const int* __restrict__ batch,
    const int* __restrict__ flag, float* __restrict__ pool, float* __restrict__ cnt)
{
    __shared__ float b2[4];
    int tid = threadIdx.x;
    if (tid < 4) b2[tid] = bg2[tid];
    __syncthreads();
    int wid = tid >> 6, lane = tid & 63;
    int i = blockIdx.x * 4 + wid;
    if (i >= NN) return;
    int beg = indptr[i], end = indptr[i + 1];
    int f = lane & 3;
    float a = 0.f;
    for (int k = beg + (lane >> 2); k < end; k += 16)
        a += h2g[(size_t)csr_src[k] * 4 + f];
    a += __shfl_xor(a, 4, 64);
    a += __shfl_xor(a, 8, 64);
    a += __shfl_xor(a, 16, 64);
    a += __shfl_xor(a, 32, 64);
    if (lane < 4) {
        float di = dinv[i];
        float h = di * (a + h2g[(size_t)i * 4 + f]) + b2[f];
        int fg = *flag;
        int b = fg ? batch[2 * i] : batch[i];
        atomAddF(&pool[(size_t)b * 4 + f], h);
        if (f == 0) atomAddF(&cnt[b], 1.f);
    }
}

// ---------------- AE encode ----------------
__global__ __launch_bounds__(256) void k_ae_encode(
    const float* __restrict__ text,
    const float* __restrict__ We1, const float* __restrict__ be1,
    const float* __restrict__ We2, const float* __restrict__ be2,
    float* __restrict__ z_text)
{
    __shared__ float red[8][256];
    __shared__ float t1[8];
    int row = blockIdx.x, tid = threadIdx.x;
    const float* xrow = text + (size_t)row * TD;
    float acc[8];
#pragma unroll
    for (int j = 0; j < 8; j++) acc[j] = 0.f;
    for (int i = tid; i < TD; i += 256) {
        float x = xrow[i];
        const float* wr = We1 + (size_t)i * 8;
#pragma unroll
        for (int j = 0; j < 8; j++) acc[j] += x * wr[j];
    }
#pragma unroll
    for (int j = 0; j < 8; j++) red[j][tid] = acc[j];
    __syncthreads();
    for (int s = 128; s > 0; s >>= 1) {
        if (tid < s) {
#pragma unroll
            for (int j = 0; j < 8; j++) red[j][tid] += red[j][tid + s];
        }
        __syncthreads();
    }
    if (tid < 8) t1[tid] = fmaxf(red[tid][0] + be1[tid], 0.f);
    __syncthreads();
    if (tid < 4) {
        float z = be2[tid];
#pragma unroll
        for (int k = 0; k < 8; k++) z += t1[k] * We2[k * 4 + tid];
        z_text[row * 4 + tid] = fmaxf(z, 0.f);
    }
}

// ---------------- final head ----------------
__global__ __launch_bounds__(256) void k_final(
    const float* __restrict__ z_text, const float* __restrict__ pool,
    const float* __restrict__ cnt, const float* __restrict__ Wc,
    const float* __restrict__ bc, float* __restrict__ out_logits,
    float* __restrict__ out_z)
{
    int g = blockIdx.x * 256 + threadIdx.x;
    if (g >= BB) return;
    float c = fmaxf(cnt[g], 1.f);
    float z8[8];
#pragma unroll
    for (int j = 0; j < 4; j++) z8[j] = z_text[g * 4 + j];
#pragma unroll
    for (int j = 0; j < 4; j++) z8[4 + j] = pool[g * 4 + j] / c;
    float l = bc[0];
#pragma unroll
    for (int k = 0; k < 8; k++) l += z8[k] * Wc[k];
    out_logits[g] = l;
#pragma unroll
    for (int k = 0; k < 8; k++) out_z[g * 8 + k] = z8[k];
}

// ---------------- AE decode (overwrites all scratch, LAST) ----------------
__global__ __launch_bounds__(256) void k_ae_decode(
    const float* __restrict__ out_z,
    const float* __restrict__ Wd1, const float* __restrict__ bd1,
    const float* __restrict__ Wd2, const float* __restrict__ bd2,
    float* __restrict__ xhat)
{
    int row = blockIdx.x, tid = threadIdx.x;
    float zz[4];
#pragma unroll
    for (int j = 0; j < 4; j++) zz[j] = out_z[row * 8 + j];
    float t[8];
#pragma unroll
    for (int k = 0; k < 8; k++) {
        float s = bd1[k];
#pragma unroll
        for (int j = 0; j < 4; j++) s += zz[j] * Wd1[j * 8 + k];
        t[k] = fmaxf(s, 0.f);
    }
    float* orow = xhat + (size_t)row * TD;
    for (int c = tid; c < TD; c += 256) {
        float s = bd2[c];
#pragma unroll
        for (int k = 0; k < 8; k++) s += t[k] * Wd2[(size_t)k * TD + c];
        orow[c] = 1.f / (1.f + expf(-s));
    }
}

extern "C" void kernel_launch(void* const* d_in, const int* in_sizes, int n_in,
                              void* d_out, int out_size, void* d_ws, size_t ws_size,
                              hipStream_t stream) {
    const float* text  = (const float*)d_in[0];
    const float* nodex = (const float*)d_in[1];
    const int* edge    = (const int*)d_in[2];
    const int* batch   = (const int*)d_in[3];
    const float* We1 = (const float*)d_in[4];
    const float* be1 = (const float*)d_in[5];
    const float* We2 = (const float*)d_in[6];
    const float* be2 = (const float*)d_in[7];
    const float* Wd1 = (const float*)d_in[8];
    const float* bd1 = (const float*)d_in[9];
    const float* Wd2 = (const float*)d_in[10];
    const float* bd2 = (const float*)d_in[11];
    const float* Wg1 = (const float*)d_in[12];
    const float* bg1 = (const float*)d_in[13];
    const float* Wg2 = (const float*)d_in[14];
    const float* bg2 = (const float*)d_in[15];
    const float* Wc  = (const float*)d_in[16];
    const float* bc  = (const float*)d_in[17];

    // d_out = 20,516,864 f32 (82,067,456 B). Scratch in x_hat region (first 81.92 MB),
    // overwritten by k_ae_decode at the end. d_ws unused.
    char* sc = (char*)d_out;
    float*        h0g    = (float*)(sc + 0);           // N*8 f32
    float*        h2g    = (float*)(sc + 6400000);     // N*4 f32
    float*        dinv   = (float*)(sc + 9600000);     // N f32
    unsigned int* deg    = (unsigned int*)(sc + 10400000); // N u32
    unsigned int* indptr = (unsigned int*)(sc + 11200000); // (N+1) u32
    unsigned int* rnk    = (unsigned int*)(sc + 12000004); // E u32
    int*          csr    = (int*)(sc + 37600004);      // E i32
    unsigned int* bsum   = (unsigned int*)(sc + 63200004);
    unsigned int* bpre   = (unsigned int*)(sc + 63203132);
    float*        pool   = (float*)(sc + 63206260);    // B*4 f32
    float*        cnt    = (float*)(sc + 63271796);    // B f32
    float*        z_text = (float*)(sc + 63288180);    // B*4 f32
    int*          flag   = (int*)(sc + 63353716);      // 4 B
    // ends ~63.35 MB < 81.92 MB (start of out_logits)

    float* out_xhat   = (float*)d_out;                 // B*TD
    float* out_logits = out_xhat + (size_t)BB * TD;    // B
    float* out_z      = out_logits + BB;               // B*8

    const int NB_E = EE / 256;           // 25000
    const int NB_G = (NN + 3) / 4;       // 50000 (wave per node)

    k_zero<<<(BB * 5 + 255) / 256, 256, 0, stream>>>(pool, BB * 5);  // pool+cnt contiguous
    k_detect<<<1, 256, 0, stream>>>(edge, flag);
    k_deg_init<<<NBK, 256, 0, stream>>>(deg);
    k_rank<<<NB_E, 256, 0, stream>>>(edge, flag, deg, rnk);

    kA_blocksum<<<NBK, 256, 0, stream>>>(deg, bsum);
    kB_scanblocks<<<1, 1024, 0, stream>>>(bsum, bpre, indptr);
    kC_indptr<<<NBK, 256, 0, stream>>>(deg, bpre, indptr);
    k_dinv<<<NBK, 256, 0, stream>>>(deg, dinv);
    k_place<<<NB_E, 256, 0, stream>>>(edge, flag, indptr, rnk, csr);

    k_gcn1_mm<<<NBK, 256, 0, stream>>>(nodex, Wg1, dinv, h0g);
    k_gather1<<<NB_G, 256, 0, stream>>>(indptr, csr, h0g, dinv, bg1, Wg2, h2g);
    k_gather2<<<NB_G, 256, 0, stream>>>(indptr, csr, h2g, dinv, bg2, batch, flag, pool, cnt);

    k_ae_encode<<<BB, 256, 0, stream>>>(text, We1, be1, We2, be2, z_text);
    k_final<<<(BB + 255) / 256, 256, 0, stream>>>(z_text, pool, cnt, Wc, bc,
                                                  out_logits, out_z);
    k_ae_decode<<<BB, 256, 0, stream>>>(out_z, Wd1, bd1, Wd2, bd2, out_xhat);
}

// Round 8
// 782.760 us; speedup vs baseline: 5.5148x; 1.0636x over previous
//
#include <hip/hip_runtime.h>

#define BB 4096
#define TD 5000
#define NN 200000
#define EE 6400000
#define NBK 782  // ceil(NN/256)

// ---------------- init: deg=1 everywhere; block 0 also detects edge dtype ----------------
// int64 edges -> every odd int32 word is 0 (values < 2^31). 4096 zero words from
// int32 edges is impossible (random node ids).
__global__ void k_init(const int* __restrict__ e, unsigned int* __restrict__ deg,
                       int* __restrict__ flag) {
    int i = blockIdx.x * 256 + threadIdx.x;
    if (i < NN) deg[i] = 1u;  // self loop
    if (blockIdx.x == 0) {
        __shared__ int r[256];
        int tid = threadIdx.x;
        int acc = 0;
        for (int k = tid; k < 4096; k += 256) acc |= e[2 * k + 1];
        r[tid] = acc;
        __syncthreads();
        for (int s = 128; s > 0; s >>= 1) {
            if (tid < s) r[tid] |= r[tid + s];
            __syncthreads();
        }
        if (tid == 0) *flag = (r[0] == 0) ? 1 : 0;
    }
}

// ONE atomic pass: per-edge rank within dst + final degree.
__global__ void k_rank(const int* __restrict__ edge, const int* __restrict__ flag,
                       unsigned int* __restrict__ deg, unsigned int* __restrict__ r) {
    int e = blockIdx.x * 256 + threadIdx.x;
    if (e >= EE) return;
    int f = *flag;
    int d = f ? edge[2 * (EE + e)] : edge[EE + e];
    r[e] = atomicAdd(&deg[d], 1u);
}

// ---------------- post-rank node pass: dinv + per-block degree sums + batch boundaries ----
__global__ void kA_all(const unsigned int* __restrict__ deg, float* __restrict__ dinv,
                       unsigned int* __restrict__ bsum, const int* __restrict__ batch,
                       const int* __restrict__ flag, unsigned int* __restrict__ bnd) {
    __shared__ unsigned int s[256];
    int tid = threadIdx.x;
    int i = blockIdx.x * 256 + tid;
    unsigned int c = 0u;
    if (i < NN) {
        unsigned int u = deg[i];
        dinv[i] = rsqrtf((float)u);
        c = u - 1u;
        int fg = *flag;
        int b = fg ? batch[2 * i] : batch[i];
        int bp = (i == 0) ? -1 : (fg ? batch[2 * (i - 1)] : batch[i - 1]);
        for (int bb = bp + 1; bb <= b; bb++) bnd[bb] = (unsigned int)i;
        if (i == NN - 1)
            for (int bb = b + 1; bb <= BB; bb++) bnd[bb] = (unsigned int)NN;
    }
    s[tid] = c;
    __syncthreads();
    for (int st = 128; st > 0; st >>= 1) {
        if (tid < st) s[tid] += s[tid + st];
        __syncthreads();
    }
    if (tid == 0) bsum[blockIdx.x] = s[0];
}

__global__ void kB_scanblocks(const unsigned int* __restrict__ bsum, unsigned int* __restrict__ bpre,
                              unsigned int* __restrict__ indptr) {
    __shared__ unsigned int s[1024];
    int t = threadIdx.x;
    s[t] = (t < NBK) ? bsum[t] : 0u;
    __syncthreads();
    for (int off = 1; off < 1024; off <<= 1) {
        unsigned int v = (t >= off) ? s[t - off] : 0u;
        __syncthreads();
        s[t] += v;
        __syncthreads();
    }
    if (t < NBK) bpre[t] = (t == 0) ? 0u : s[t - 1];
    if (t == 0) indptr[NN] = EE;
}

__global__ void kC_indptr(const unsigned int* __restrict__ deg, const unsigned int* __restrict__ bpre,
                          unsigned int* __restrict__ indptr) {
    __shared__ unsigned int s[256];
    int tid = threadIdx.x;
    int i = blockIdx.x * 256 + tid;
    unsigned int c = (i < NN) ? (deg[i] - 1u) : 0u;
    s[tid] = c;
    __syncthreads();
    for (int off = 1; off < 256; off <<= 1) {
        unsigned int v = (tid >= off) ? s[tid - off] : 0u;
        __syncthreads();
        s[tid] += v;
        __syncthreads();
    }
    if (i < NN) indptr[i] = bpre[blockIdx.x] + s[tid] - c;  // exclusive
}

// atomic-free placement
__global__ void k_place(const int* __restrict__ edge, const int* __restrict__ flag,
                        const unsigned int* __restrict__ indptr, const unsigned int* __restrict__ r,
                        int* __restrict__ csr_src) {
    int e = blockIdx.x * 256 + threadIdx.x;
    if (e >= EE) return;
    int f = *flag;
    int s = f ? edge[2 * e] : edge[e];
    int d = f ? edge[2 * (EE + e)] : edge[EE + e];
    csr_src[indptr[d] + r[e] - 1u] = s;
}

// ---------------- GCN ----------------
// h0g = dinv[i] * (node_x @ Wg1)   (128 -> 8)
__global__ __launch_bounds__(256) void k_gcn1_mm(
    const float* __restrict__ nodex, const float* __restrict__ Wg1,
    const float* __restrict__ dinv, float* __restrict__ h0g)
{
    __shared__ float W[128 * 8];
    int tid = threadIdx.x;
    for (int i = tid; i < 1024; i += 256) W[i] = Wg1[i];
    __syncthreads();
    int row = blockIdx.x * 256 + tid;
    if (row >= NN) return;
    const float4* xr = (const float4*)(nodex + (size_t)row * 128);
    float acc[8];
#pragma unroll
    for (int j = 0; j < 8; j++) acc[j] = 0.f;
#pragma unroll 8
    for (int c = 0; c < 32; c++) {
        float4 v = xr[c];
        const float* wr = &W[c * 32];
#pragma unroll
        for (int j = 0; j < 8; j++)
            acc[j] += v.x * wr[j] + v.y * wr[8 + j] + v.z * wr[16 + j] + v.w * wr[24 + j];
    }
    float di = dinv[row];
    float* o = h0g + (size_t)row * 8;
#pragma unroll
    for (int j = 0; j < 8; j++) o[j] = di * acc[j];
}

// wave per node: h1 = relu(dinv*(h0g[i]+sum_in h0g[s]) + b1); h2g = dinv*(h1@Wg2)
__global__ __launch_bounds__(256) void k_gather1(
    const unsigned int* __restrict__ indptr, const int* __restrict__ csr_src,
    const float* __restrict__ h0g, const float* __restrict__ dinv,
    const float* __restrict__ bg1, const float* __restrict__ Wg2,
    float* __restrict__ h2g)
{
    __shared__ float W[32];
    __shared__ float b1[8];
    __shared__ float h1s[4][8];
    int tid = threadIdx.x;
    if (tid < 32) W[tid] = Wg2[tid];
    if (tid < 8) b1[tid] = bg1[tid];
    __syncthreads();
    int wid = tid >> 6, lane = tid & 63;
    int i = blockIdx.x * 4 + wid;
    if (i < NN) {
        int beg = indptr[i], end = indptr[i + 1];
        int f = lane & 7;
        float a = 0.f;
        for (int k = beg + (lane >> 3); k < end; k += 8)
            a += h0g[(size_t)csr_src[k] * 8 + f];
        a += __shfl_xor(a, 8, 64);
        a += __shfl_xor(a, 16, 64);
        a += __shfl_xor(a, 32, 64);
        if (lane < 8) {
            float di = dinv[i];
            h1s[wid][f] = fmaxf(di * (a + h0g[(size_t)i * 8 + f]) + b1[f], 0.f);
        }
    }
    __syncthreads();
    if (i < NN && lane < 4) {
        float di = dinv[i];
        float s = 0.f;
#pragma unroll
        for (int k = 0; k < 8; k++) s += h1s[wid][k] * W[k * 4 + lane];
        h2g[(size_t)i * 4 + lane] = di * s;
    }
}

// wave per node: h2f = dinv*(h2g[i]+sum_in h2g[s]) + b2   (coalesced store, no atomics)
__global__ __launch_bounds__(256) void k_gather2(
    const unsigned int* __restrict__ indptr, const int* __restrict__ csr_src,
    const float* __restrict__ h2g, const float* __restrict__ dinv,
    const float* __restrict__ bg2, float* __restrict__ h2f)
{
    __shared__ float b2[4];
    int tid = threadIdx.x;
    if (tid < 4) b2[tid] = bg2[tid];
    __syncthreads();
    int wid = tid >> 6, lane = tid & 63;
    int i = blockIdx.x * 4 + wid;
    if (i >= NN) return;
    int beg = indptr[i], end = indptr[i + 1];
    int f = lane & 3;
    float a = 0.f;
    for (int k = beg + (lane >> 2); k < end; k += 16)
        a += h2g[(size_t)csr_src[k] * 4 + f];
    a += __shfl_xor(a, 4, 64);
    a += __shfl_xor(a, 8, 64);
    a += __shfl_xor(a, 16, 64);
    a += __shfl_xor(a, 32, 64);
    if (lane < 4) {
        float di = dinv[i];
        h2f[(size_t)i * 4 + f] = di * (a + h2g[(size_t)i * 4 + f]) + b2[f];
    }
}

// ---------------- AE encode (float4 loads) ----------------
__global__ __launch_bounds__(256) void k_ae_encode(
    const float* __restrict__ text,
    const float* __restrict__ We1, const float* __restrict__ be1,
    const float* __restrict__ We2, const float* __restrict__ be2,
    float* __restrict__ z_text)
{
    __shared__ float red[8][256];
    __shared__ float t1[8];
    int row = blockIdx.x, tid = threadIdx.x;
    const float4* xrow = (const float4*)(text + (size_t)row * TD);  // 1250 vec4
    float acc[8];
#pragma unroll
    for (int j = 0; j < 8; j++) acc[j] = 0.f;
    for (int v = tid; v < 1250; v += 256) {
        float4 xv = xrow[v];
        const float4* w = (const float4*)(We1 + (size_t)v * 32);
        float xc[4] = {xv.x, xv.y, xv.z, xv.w};
#pragma unroll
        for (int c = 0; c < 4; c++) {
            float4 wa = w[c * 2], wb = w[c * 2 + 1];
            acc[0] += xc[c] * wa.x; acc[1] += xc[c] * wa.y;
            acc[2] += xc[c] * wa.z; acc[3] += xc[c] * wa.w;
            acc[4] += xc[c] * wb.x; acc[5] += xc[c] * wb.y;
            acc[6] += xc[c] * wb.z; acc[7] += xc[c] * wb.w;
        }
    }
#pragma unroll
    for (int j = 0; j < 8; j++) red[j][tid] = acc[j];
    __syncthreads();
    for (int s = 128; s > 0; s >>= 1) {
        if (tid < s) {
#pragma unroll
            for (int j = 0; j < 8; j++) red[j][tid] += red[j][tid + s];
        }
        __syncthreads();
    }
    if (tid < 8) t1[tid] = fmaxf(red[tid][0] + be1[tid], 0.f);
    __syncthreads();
    if (tid < 4) {
        float z = be2[tid];
#pragma unroll
        for (int k = 0; k < 8; k++) z += t1[k] * We2[k * 4 + tid];
        z_text[row * 4 + tid] = fmaxf(z, 0.f);
    }
}

// ---------------- final head: block per graph, segment-sum pool (batch sorted) ----------
__global__ __launch_bounds__(256) void k_final(
    const float* __restrict__ h2f, const unsigned int* __restrict__ bnd,
    const float* __restrict__ z_text, const float* __restrict__ Wc,
    const float* __restrict__ bc, float* __restrict__ out_logits,
    float* __restrict__ out_z)
{
    __shared__ float red[256][4];
    int g = blockIdx.x, tid = threadIdx.x;
    int lo = bnd[g], hi = bnd[g + 1];
    float a0 = 0.f, a1 = 0.f, a2 = 0.f, a3 = 0.f;
    for (int i = lo + tid; i < hi; i += 256) {
        float4 v = *(const float4*)(h2f + (size_t)i * 4);
        a0 += v.x; a1 += v.y; a2 += v.z; a3 += v.w;
    }
    red[tid][0] = a0; red[tid][1] = a1; red[tid][2] = a2; red[tid][3] = a3;
    __syncthreads();
    for (int s = 128; s > 0; s >>= 1) {
        if (tid < s) {
            red[tid][0] += red[tid + s][0]; red[tid][1] += red[tid + s][1];
            red[tid][2] += red[tid + s][2]; red[tid][3] += red[tid + s][3];
        }
        __syncthreads();
    }
    if (tid == 0) {
        float c = (float)(hi - lo);
        c = fmaxf(c, 1.f);
        float z8[8];
#pragma unroll
        for (int j = 0; j < 4; j++) z8[j] = z_text[g * 4 + j];
#pragma unroll
        for (int j = 0; j < 4; j++) z8[4 + j] = red[0][j] / c;
        float l = bc[0];
#pragma unroll
        for (int k = 0; k < 8; k++) l += z8[k] * Wc[k];
        out_logits[g] = l;
#pragma unroll
        for (int k = 0; k < 8; k++) out_z[g * 8 + k] = z8[k];
    }
}

// ---------------- AE decode (float4 stores; overwrites all scratch, LAST) ----------------
__global__ __launch_bounds__(256) void k_ae_decode(
    const float* __restrict__ out_z,
    const float* __restrict__ Wd1, const float* __restrict__ bd1,
    const float* __restrict__ Wd2, const float* __restrict__ bd2,
    float* __restrict__ xhat)
{
    int row = blockIdx.x, tid = threadIdx.x;
    float zz[4];
#pragma unroll
    for (int j = 0; j < 4; j++) zz[j] = out_z[row * 8 + j];
    float t[8];
#pragma unroll
    for (int k = 0; k < 8; k++) {
        float s = bd1[k];
#pragma unroll
        for (int j = 0; j < 4; j++) s += zz[j] * Wd1[j * 8 + k];
        t[k] = fmaxf(s, 0.f);
    }
    float4* orow = (float4*)(xhat + (size_t)row * TD);  // 1250 vec4
    for (int c4 = tid; c4 < 1250; c4 += 256) {
        float4 s = *(const float4*)(bd2 + c4 * 4);
#pragma unroll
        for (int k = 0; k < 8; k++) {
            float4 w = *(const float4*)(Wd2 + (size_t)k * TD + c4 * 4);
            s.x += t[k] * w.x; s.y += t[k] * w.y;
            s.z += t[k] * w.z; s.w += t[k] * w.w;
        }
        s.x = 1.f / (1.f + expf(-s.x));
        s.y = 1.f / (1.f + expf(-s.y));
        s.z = 1.f / (1.f + expf(-s.z));
        s.w = 1.f / (1.f + expf(-s.w));
        orow[c4] = s;
    }
}

extern "C" void kernel_launch(void* const* d_in, const int* in_sizes, int n_in,
                              void* d_out, int out_size, void* d_ws, size_t ws_size,
                              hipStream_t stream) {
    const float* text  = (const float*)d_in[0];
    const float* nodex = (const float*)d_in[1];
    const int* edge    = (const int*)d_in[2];
    const int* batch   = (const int*)d_in[3];
    const float* We1 = (const float*)d_in[4];
    const float* be1 = (const float*)d_in[5];
    const float* We2 = (const float*)d_in[6];
    const float* be2 = (const float*)d_in[7];
    const float* Wd1 = (const float*)d_in[8];
    const float* bd1 = (const float*)d_in[9];
    const float* Wd2 = (const float*)d_in[10];
    const float* bd2 = (const float*)d_in[11];
    const float* Wg1 = (const float*)d_in[12];
    const float* bg1 = (const float*)d_in[13];
    const float* Wg2 = (const float*)d_in[14];
    const float* bg2 = (const float*)d_in[15];
    const float* Wc  = (const float*)d_in[16];
    const float* bc  = (const float*)d_in[17];

    // d_out = 20,516,864 f32. Scratch in x_hat region (first 81.92 MB),
    // overwritten by k_ae_decode at the end. d_ws unused.
    char* sc = (char*)d_out;
    float*        h0g    = (float*)(sc + 0);               // N*8 f32 = 6.4 MB
    float*        h2g    = (float*)(sc + 6400000);         // N*4 f32
    float*        h2f    = (float*)(sc + 9600000);         // N*4 f32
    float*        dinv   = (float*)(sc + 12800000);        // N f32
    unsigned int* deg    = (unsigned int*)(sc + 13600000); // N u32
    unsigned int* indptr = (unsigned int*)(sc + 14400000); // (N+1) u32
    unsigned int* rnk    = (unsigned int*)(sc + 15200004); // E u32 -> ends 40,800,004
    int*          csr    = (int*)(sc + 40800004);          // E i32 -> ends 66,400,004
    unsigned int* bsum   = (unsigned int*)(sc + 66400004); // NBK u32
    unsigned int* bpre   = (unsigned int*)(sc + 66403132); // NBK u32
    float*        z_text = (float*)(sc + 66406260);        // B*4 f32
    unsigned int* bnd    = (unsigned int*)(sc + 66471796); // (B+1) u32
    int*          flag   = (int*)(sc + 66488184);          // 4 B
    // ends ~66.5 MB < 81.92 MB (start of out_logits)

    float* out_xhat   = (float*)d_out;
    float* out_logits = out_xhat + (size_t)BB * TD;
    float* out_z      = out_logits + BB;

    const int NB_E = EE / 256;      // 25000
    const int NB_G = (NN + 3) / 4;  // 50000

    k_init<<<NBK, 256, 0, stream>>>(edge, deg, flag);
    k_rank<<<NB_E, 256, 0, stream>>>(edge, flag, deg, rnk);
    kA_all<<<NBK, 256, 0, stream>>>(deg, dinv, bsum, batch, flag, bnd);
    kB_scanblocks<<<1, 1024, 0, stream>>>(bsum, bpre, indptr);
    kC_indptr<<<NBK, 256, 0, stream>>>(deg, bpre, indptr);
    k_place<<<NB_E, 256, 0, stream>>>(edge, flag, indptr, rnk, csr);

    k_gcn1_mm<<<NBK, 256, 0, stream>>>(nodex, Wg1, dinv, h0g);
    k_gather1<<<NB_G, 256, 0, stream>>>(indptr, csr, h0g, dinv, bg1, Wg2, h2g);
    k_gather2<<<NB_G, 256, 0, stream>>>(indptr, csr, h2g, dinv, bg2, h2f);

    k_ae_encode<<<BB, 256, 0, stream>>>(text, We1, be1, We2, be2, z_text);
    k_final<<<BB, 256, 0, stream>>>(h2f, bnd, z_text, Wc, bc, out_logits, out_z);
    k_ae_decode<<<BB, 256, 0, stream>>>(out_z, Wd1, bd1, Wd2, bd2, out_xhat);
}

// Round 9
// 723.073 us; speedup vs baseline: 5.9700x; 1.0825x over previous
//
#include <hip/hip_runtime.h>

#define BB 4096
#define TD 5000
#define NN 200000
#define EE 6400000
#define NBK 782  // ceil(NN/256)

// ---------------- init: deg=1 everywhere; block 0 also detects edge dtype ----------------
__global__ void k_init(const int* __restrict__ e, unsigned int* __restrict__ deg,
                       int* __restrict__ flag) {
    int i = blockIdx.x * 256 + threadIdx.x;
    if (i < NN) deg[i] = 1u;  // self loop
    if (blockIdx.x == 0) {
        __shared__ int r[256];
        int tid = threadIdx.x;
        int acc = 0;
        for (int k = tid; k < 4096; k += 256) acc |= e[2 * k + 1];
        r[tid] = acc;
        __syncthreads();
        for (int s = 128; s > 0; s >>= 1) {
            if (tid < s) r[tid] |= r[tid + s];
            __syncthreads();
        }
        if (tid == 0) *flag = (r[0] == 0) ? 1 : 0;
    }
}

// ---------------- fat kernel: rank (8 edges/thread, 3125 blocks) + AE encode (4096 blocks)
// Interleaved roles: bid<6250 -> even=rank(bid>>1), odd=encode(bid>>1);
// bid>=6250 -> encode(3125 + bid - 6250). Total grid = 7221.
__global__ __launch_bounds__(256) void k_rank_enc(
    const int* __restrict__ edge, const int* __restrict__ flag,
    unsigned int* __restrict__ deg, unsigned int* __restrict__ rnk,
    const float* __restrict__ text,
    const float* __restrict__ We1, const float* __restrict__ be1,
    const float* __restrict__ We2, const float* __restrict__ be2,
    float* __restrict__ z_text)
{
    __shared__ float red[8][256];
    __shared__ float t1[8];
    int bid = blockIdx.x, tid = threadIdx.x;
    int enc_id = -1, rank_id = -1;
    if (bid < 6250) {
        if (bid & 1) enc_id = bid >> 1;
        else rank_id = bid >> 1;
    } else {
        enc_id = 3125 + (bid - 6250);
    }

    if (rank_id >= 0) {
        // ---- rank role: 8 independent atomics in flight per thread ----
        int f = *flag;
        int base = rank_id * 2048 + tid;
        int d[8];
#pragma unroll
        for (int k = 0; k < 8; k++) {
            int e = base + k * 256;
            d[k] = f ? edge[2 * (EE + e)] : edge[EE + e];
        }
        unsigned int rr[8];
#pragma unroll
        for (int k = 0; k < 8; k++) rr[k] = atomicAdd(&deg[d[k]], 1u);
#pragma unroll
        for (int k = 0; k < 8; k++) rnk[base + k * 256] = rr[k];
        return;
    }

    // ---- encode role ----
    int row = enc_id;
    const float4* xrow = (const float4*)(text + (size_t)row * TD);  // 1250 vec4
    float acc[8];
#pragma unroll
    for (int j = 0; j < 8; j++) acc[j] = 0.f;
    for (int v = tid; v < 1250; v += 256) {
        float4 xv = xrow[v];
        const float4* w = (const float4*)(We1 + (size_t)v * 32);
        float xc[4] = {xv.x, xv.y, xv.z, xv.w};
#pragma unroll
        for (int c = 0; c < 4; c++) {
            float4 wa = w[c * 2], wb = w[c * 2 + 1];
            acc[0] += xc[c] * wa.x; acc[1] += xc[c] * wa.y;
            acc[2] += xc[c] * wa.z; acc[3] += xc[c] * wa.w;
            acc[4] += xc[c] * wb.x; acc[5] += xc[c] * wb.y;
            acc[6] += xc[c] * wb.z; acc[7] += xc[c] * wb.w;
        }
    }
#pragma unroll
    for (int j = 0; j < 8; j++) red[j][tid] = acc[j];
    __syncthreads();
    for (int s = 128; s > 0; s >>= 1) {
        if (tid < s) {
#pragma unroll
            for (int j = 0; j < 8; j++) red[j][tid] += red[j][tid + s];
        }
        __syncthreads();
    }
    if (tid < 8) t1[tid] = fmaxf(red[tid][0] + be1[tid], 0.f);
    __syncthreads();
    if (tid < 4) {
        float z = be2[tid];
#pragma unroll
        for (int k = 0; k < 8; k++) z += t1[k] * We2[k * 4 + tid];
        z_text[row * 4 + tid] = fmaxf(z, 0.f);
    }
}

// ---------------- post-rank node pass: dinv + per-block degree sums + batch boundaries ----
__global__ void kA_all(const unsigned int* __restrict__ deg, float* __restrict__ dinv,
                       unsigned int* __restrict__ bsum, const int* __restrict__ batch,
                       const int* __restrict__ flag, unsigned int* __restrict__ bnd) {
    __shared__ unsigned int s[256];
    int tid = threadIdx.x;
    int i = blockIdx.x * 256 + tid;
    unsigned int c = 0u;
    if (i < NN) {
        unsigned int u = deg[i];
        dinv[i] = rsqrtf((float)u);
        c = u - 1u;
        int fg = *flag;
        int b = fg ? batch[2 * i] : batch[i];
        int bp = (i == 0) ? -1 : (fg ? batch[2 * (i - 1)] : batch[i - 1]);
        for (int bb = bp + 1; bb <= b; bb++) bnd[bb] = (unsigned int)i;
        if (i == NN - 1)
            for (int bb = b + 1; bb <= BB; bb++) bnd[bb] = (unsigned int)NN;
    }
    s[tid] = c;
    __syncthreads();
    for (int st = 128; st > 0; st >>= 1) {
        if (tid < st) s[tid] += s[tid + st];
        __syncthreads();
    }
    if (tid == 0) bsum[blockIdx.x] = s[0];
}

__global__ void kB_scanblocks(const unsigned int* __restrict__ bsum, unsigned int* __restrict__ bpre,
                              unsigned int* __restrict__ indptr) {
    __shared__ unsigned int s[1024];
    int t = threadIdx.x;
    s[t] = (t < NBK) ? bsum[t] : 0u;
    __syncthreads();
    for (int off = 1; off < 1024; off <<= 1) {
        unsigned int v = (t >= off) ? s[t - off] : 0u;
        __syncthreads();
        s[t] += v;
        __syncthreads();
    }
    if (t < NBK) bpre[t] = (t == 0) ? 0u : s[t - 1];
    if (t == 0) indptr[NN] = EE;
}

__global__ void kC_indptr(const unsigned int* __restrict__ deg, const unsigned int* __restrict__ bpre,
                          unsigned int* __restrict__ indptr) {
    __shared__ unsigned int s[256];
    int tid = threadIdx.x;
    int i = blockIdx.x * 256 + tid;
    unsigned int c = (i < NN) ? (deg[i] - 1u) : 0u;
    s[tid] = c;
    __syncthreads();
    for (int off = 1; off < 256; off <<= 1) {
        unsigned int v = (tid >= off) ? s[tid - off] : 0u;
        __syncthreads();
        s[tid] += v;
        __syncthreads();
    }
    if (i < NN) indptr[i] = bpre[blockIdx.x] + s[tid] - c;  // exclusive
}

// atomic-free placement, 4 edges/thread (6250 blocks, exact)
__global__ void k_place(const int* __restrict__ edge, const int* __restrict__ flag,
                        const unsigned int* __restrict__ indptr, const unsigned int* __restrict__ rnk,
                        int* __restrict__ csr) {
    int f = *flag;
    int base = blockIdx.x * 1024 + threadIdx.x;
    int s[4], d[4];
#pragma unroll
    for (int k = 0; k < 4; k++) {
        int e = base + k * 256;
        s[k] = f ? edge[2 * e] : edge[e];
        d[k] = f ? edge[2 * (EE + e)] : edge[EE + e];
    }
    unsigned int rr[4];
#pragma unroll
    for (int k = 0; k < 4; k++) rr[k] = rnk[base + k * 256];
    unsigned int ip[4];
#pragma unroll
    for (int k = 0; k < 4; k++) ip[k] = indptr[d[k]];
#pragma unroll
    for (int k = 0; k < 4; k++) csr[ip[k] + rr[k] - 1u] = s[k];
}

// ---------------- GCN ----------------
__global__ __launch_bounds__(256) void k_gcn1_mm(
    const float* __restrict__ nodex, const float* __restrict__ Wg1,
    const float* __restrict__ dinv, float* __restrict__ h0g)
{
    __shared__ float W[128 * 8];
    int tid = threadIdx.x;
    for (int i = tid; i < 1024; i += 256) W[i] = Wg1[i];
    __syncthreads();
    int row = blockIdx.x * 256 + tid;
    if (row >= NN) return;
    const float4* xr = (const float4*)(nodex + (size_t)row * 128);
    float acc[8];
#pragma unroll
    for (int j = 0; j < 8; j++) acc[j] = 0.f;
#pragma unroll 8
    for (int c = 0; c < 32; c++) {
        float4 v = xr[c];
        const float* wr = &W[c * 32];
#pragma unroll
        for (int j = 0; j < 8; j++)
            acc[j] += v.x * wr[j] + v.y * wr[8 + j] + v.z * wr[16 + j] + v.w * wr[24 + j];
    }
    float di = dinv[row];
    float* o = h0g + (size_t)row * 8;
#pragma unroll
    for (int j = 0; j < 8; j++) o[j] = di * acc[j];
}

__global__ __launch_bounds__(256) void k_gather1(
    const unsigned int* __restrict__ indptr, const int* __restrict__ csr_src,
    const float* __restrict__ h0g, const float* __restrict__ dinv,
    const float* __restrict__ bg1, const float* __restrict__ Wg2,
    float* __restrict__ h2g)
{
    __shared__ float W[32];
    __shared__ float b1[8];
    __shared__ float h1s[4][8];
    int tid = threadIdx.x;
    if (tid < 32) W[tid] = Wg2[tid];
    if (tid < 8) b1[tid] = bg1[tid];
    __syncthreads();
    int wid = tid >> 6, lane = tid & 63;
    int i = blockIdx.x * 4 + wid;
    if (i < NN) {
        int beg = indptr[i], end = indptr[i + 1];
        int f = lane & 7;
        float a = 0.f;
        for (int k = beg + (lane >> 3); k < end; k += 8)
            a += h0g[(size_t)csr_src[k] * 8 + f];
        a += __shfl_xor(a, 8, 64);
        a += __shfl_xor(a, 16, 64);
        a += __shfl_xor(a, 32, 64);
        if (lane < 8) {
            float di = dinv[i];
            h1s[wid][f] = fmaxf(di * (a + h0g[(size_t)i * 8 + f]) + b1[f], 0.f);
        }
    }
    __syncthreads();
    if (i < NN && lane < 4) {
        float di = dinv[i];
        float s = 0.f;
#pragma unroll
        for (int k = 0; k < 8; k++) s += h1s[wid][k] * W[k * 4 + lane];
        h2g[(size_t)i * 4 + lane] = di * s;
    }
}

__global__ __launch_bounds__(256) void k_gather2(
    const unsigned int* __restrict__ indptr, const int* __restrict__ csr_src,
    const float* __restrict__ h2g, const float* __restrict__ dinv,
    const float* __restrict__ bg2, float* __restrict__ h2f)
{
    __shared__ float b2[4];
    int tid = threadIdx.x;
    if (tid < 4) b2[tid] = bg2[tid];
    __syncthreads();
    int wid = tid >> 6, lane = tid & 63;
    int i = blockIdx.x * 4 + wid;
    if (i >= NN) return;
    int beg = indptr[i], end = indptr[i + 1];
    int f = lane & 3;
    float a = 0.f;
    for (int k = beg + (lane >> 2); k < end; k += 16)
        a += h2g[(size_t)csr_src[k] * 4 + f];
    a += __shfl_xor(a, 4, 64);
    a += __shfl_xor(a, 8, 64);
    a += __shfl_xor(a, 16, 64);
    a += __shfl_xor(a, 32, 64);
    if (lane < 4) {
        float di = dinv[i];
        h2f[(size_t)i * 4 + f] = di * (a + h2g[(size_t)i * 4 + f]) + b2[f];
    }
}

// ---------------- final head: block per graph, segment-sum pool (batch sorted) ----------
__global__ __launch_bounds__(256) void k_final(
    const float* __restrict__ h2f, const unsigned int* __restrict__ bnd,
    const float* __restrict__ z_text, const float* __restrict__ Wc,
    const float* __restrict__ bc, float* __restrict__ out_logits,
    float* __restrict__ out_z)
{
    __shared__ float red[256][4];
    int g = blockIdx.x, tid = threadIdx.x;
    int lo = bnd[g], hi = bnd[g + 1];
    float a0 = 0.f, a1 = 0.f, a2 = 0.f, a3 = 0.f;
    for (int i = lo + tid; i < hi; i += 256) {
        float4 v = *(const float4*)(h2f + (size_t)i * 4);
        a0 += v.x; a1 += v.y; a2 += v.z; a3 += v.w;
    }
    red[tid][0] = a0; red[tid][1] = a1; red[tid][2] = a2; red[tid][3] = a3;
    __syncthreads();
    for (int s = 128; s > 0; s >>= 1) {
        if (tid < s) {
            red[tid][0] += red[tid + s][0]; red[tid][1] += red[tid + s][1];
            red[tid][2] += red[tid + s][2]; red[tid][3] += red[tid + s][3];
        }
        __syncthreads();
    }
    if (tid == 0) {
        float c = (float)(hi - lo);
        c = fmaxf(c, 1.f);
        float z8[8];
#pragma unroll
        for (int j = 0; j < 4; j++) z8[j] = z_text[g * 4 + j];
#pragma unroll
        for (int j = 0; j < 4; j++) z8[4 + j] = red[0][j] / c;
        float l = bc[0];
#pragma unroll
        for (int k = 0; k < 8; k++) l += z8[k] * Wc[k];
        out_logits[g] = l;
#pragma unroll
        for (int k = 0; k < 8; k++) out_z[g * 8 + k] = z8[k];
    }
}

// ---------------- AE decode (float4 stores; overwrites all scratch, LAST) ----------------
__global__ __launch_bounds__(256) void k_ae_decode(
    const float* __restrict__ out_z,
    const float* __restrict__ Wd1, const float* __restrict__ bd1,
    const float* __restrict__ Wd2, const float* __restrict__ bd2,
    float* __restrict__ xhat)
{
    int row = blockIdx.x, tid = threadIdx.x;
    float zz[4];
#pragma unroll
    for (int j = 0; j < 4; j++) zz[j] = out_z[row * 8 + j];
    float t[8];
#pragma unroll
    for (int k = 0; k < 8; k++) {
        float s = bd1[k];
#pragma unroll
        for (int j = 0; j < 4; j++) s += zz[j] * Wd1[j * 8 + k];
        t[k] = fmaxf(s, 0.f);
    }
    float4* orow = (float4*)(xhat + (size_t)row * TD);  // 1250 vec4
    for (int c4 = tid; c4 < 1250; c4 += 256) {
        float4 s = *(const float4*)(bd2 + c4 * 4);
#pragma unroll
        for (int k = 0; k < 8; k++) {
            float4 w = *(const float4*)(Wd2 + (size_t)k * TD + c4 * 4);
            s.x += t[k] * w.x; s.y += t[k] * w.y;
            s.z += t[k] * w.z; s.w += t[k] * w.w;
        }
        s.x = 1.f / (1.f + expf(-s.x));
        s.y = 1.f / (1.f + expf(-s.y));
        s.z = 1.f / (1.f + expf(-s.z));
        s.w = 1.f / (1.f + expf(-s.w));
        orow[c4] = s;
    }
}

extern "C" void kernel_launch(void* const* d_in, const int* in_sizes, int n_in,
                              void* d_out, int out_size, void* d_ws, size_t ws_size,
                              hipStream_t stream) {
    const float* text  = (const float*)d_in[0];
    const float* nodex = (const float*)d_in[1];
    const int* edge    = (const int*)d_in[2];
    const int* batch   = (const int*)d_in[3];
    const float* We1 = (const float*)d_in[4];
    const float* be1 = (const float*)d_in[5];
    const float* We2 = (const float*)d_in[6];
    const float* be2 = (const float*)d_in[7];
    const float* Wd1 = (const float*)d_in[8];
    const float* bd1 = (const float*)d_in[9];
    const float* Wd2 = (const float*)d_in[10];
    const float* bd2 = (const float*)d_in[11];
    const float* Wg1 = (const float*)d_in[12];
    const float* bg1 = (const float*)d_in[13];
    const float* Wg2 = (const float*)d_in[14];
    const float* bg2 = (const float*)d_in[15];
    const float* Wc  = (const float*)d_in[16];
    const float* bc  = (const float*)d_in[17];

    // d_out = 20,516,864 f32. Scratch in x_hat region (first 81.92 MB),
    // overwritten by k_ae_decode at the end. d_ws unused.
    char* sc = (char*)d_out;
    float*        h0g    = (float*)(sc + 0);               // N*8 f32
    float*        h2g    = (float*)(sc + 6400000);         // N*4 f32
    float*        h2f    = (float*)(sc + 9600000);         // N*4 f32
    float*        dinv   = (float*)(sc + 12800000);        // N f32
    unsigned int* deg    = (unsigned int*)(sc + 13600000); // N u32
    unsigned int* indptr = (unsigned int*)(sc + 14400000); // (N+1) u32
    unsigned int* rnk    = (unsigned int*)(sc + 15200004); // E u32 -> ends 40,800,004
    int*          csr    = (int*)(sc + 40800004);          // E i32 -> ends 66,400,004
    unsigned int* bsum   = (unsigned int*)(sc + 66400004); // NBK u32
    unsigned int* bpre   = (unsigned int*)(sc + 66403132); // NBK u32
    float*        z_text = (float*)(sc + 66406260);        // B*4 f32
    unsigned int* bnd    = (unsigned int*)(sc + 66471796); // (B+1) u32
    int*          flag   = (int*)(sc + 66488184);          // 4 B

    float* out_xhat   = (float*)d_out;
    float* out_logits = out_xhat + (size_t)BB * TD;
    float* out_z      = out_logits + BB;

    k_init<<<NBK, 256, 0, stream>>>(edge, deg, flag);
    k_rank_enc<<<7221, 256, 0, stream>>>(edge, flag, deg, rnk,
                                         text, We1, be1, We2, be2, z_text);
    kA_all<<<NBK, 256, 0, stream>>>(deg, dinv, bsum, batch, flag, bnd);
    kB_scanblocks<<<1, 1024, 0, stream>>>(bsum, bpre, indptr);
    kC_indptr<<<NBK, 256, 0, stream>>>(deg, bpre, indptr);
    k_place<<<6250, 256, 0, stream>>>(edge, flag, indptr, rnk, csr);

    k_gcn1_mm<<<NBK, 256, 0, stream>>>(nodex, Wg1, dinv, h0g);
    k_gather1<<<(NN + 3) / 4, 256, 0, stream>>>(indptr, csr, h0g, dinv, bg1, Wg2, h2g);
    k_gather2<<<(NN + 3) / 4, 256, 0, stream>>>(indptr, csr, h2g, dinv, bg2, h2f);

    k_final<<<BB, 256, 0, stream>>>(h2f, bnd, z_text, Wc, bc, out_logits, out_z);
    k_ae_decode<<<BB, 256, 0, stream>>>(out_z, Wd1, bd1, Wd2, bd2, out_xhat);
}